// Round 14
// baseline (249.149 us; speedup 1.0000x reference)
//
#include <hip/hip_runtime.h>
#include <hip/hip_bf16.h>
#include <stdint.h>
#include <math.h>

#define B_ 4
#define T_ 2048
#define E_ 1024
#define H_ 16
#define D_ 64

typedef __attribute__((ext_vector_type(8))) short short8;
typedef __attribute__((ext_vector_type(4))) short short4v;
typedef __attribute__((ext_vector_type(4))) float f32x4;

#define MFMA_BF16(a, b, c) __builtin_amdgcn_mfma_f32_16x16x32_bf16((a), (b), (c), 0, 0, 0)

__device__ __forceinline__ unsigned short f2bf(float f) {
  union { float f; unsigned u; } v; v.f = f;
  unsigned r = v.u + 0x7FFFu + ((v.u >> 16) & 1u);  // RNE
  return (unsigned short)(r >> 16);
}

#define GLOAD_LDS16(g, l)                                                        \
  __builtin_amdgcn_global_load_lds((const __attribute__((address_space(1))) void*)(g), \
                                   (__attribute__((address_space(3))) void*)(l), 16, 0, 0)

// ---------------- fp32 -> bf16 convert (vectorized) ----------------
__global__ __launch_bounds__(256) void cvt_f32_bf16(const float* __restrict__ in,
                                                    unsigned short* __restrict__ out,
                                                    int n8) {
  int i = blockIdx.x * blockDim.x + threadIdx.x;
  if (i >= n8) return;
  const float4* p = (const float4*)(in + (size_t)i * 8);
  float4 a = p[0], b = p[1];
  short8 r;
  r[0] = (short)f2bf(a.x); r[1] = (short)f2bf(a.y);
  r[2] = (short)f2bf(a.z); r[3] = (short)f2bf(a.w);
  r[4] = (short)f2bf(b.x); r[5] = (short)f2bf(b.y);
  r[6] = (short)f2bf(b.z); r[7] = (short)f2bf(b.w);
  *(short8*)(out + (size_t)i * 8) = r;
}

// 4 weight matrices in one launch (dest regions contiguous in ws)
__global__ __launch_bounds__(256) void cvt_w4(const float* __restrict__ w0,
                                              const float* __restrict__ w1,
                                              const float* __restrict__ w2,
                                              const float* __restrict__ w3,
                                              unsigned short* __restrict__ out) {
  int i = blockIdx.x * blockDim.x + threadIdx.x;  // one per 8 elems
  int which = i >> 17;                            // WE/8 = 2^17
  int off = i & 131071;
  const float* src = (which == 0) ? w0 : (which == 1) ? w1 : (which == 2) ? w2 : w3;
  const float4* p = (const float4*)(src + (size_t)off * 8);
  float4 a = p[0], b = p[1];
  short8 r;
  r[0] = (short)f2bf(a.x); r[1] = (short)f2bf(a.y);
  r[2] = (short)f2bf(a.z); r[3] = (short)f2bf(a.w);
  r[4] = (short)f2bf(b.x); r[5] = (short)f2bf(b.y);
  r[6] = (short)f2bf(b.z); r[7] = (short)f2bf(b.w);
  *(short8*)(out + ((size_t)which << 20) + (size_t)off * 8) = r;
}

// ---------------- fused QKV GEMM: C = x * W^T for W in {Wq,Wk,Wv} -------------
// sel 0/1 (Q,K): bf16 [B*H][T][D]. sel 2 (V): bf16 TRANSPOSED [B*H][D][T] via
// packed 8B stores (4 consecutive t at fixed d).
__global__ __launch_bounds__(256) void gemm_qkv(const unsigned short* __restrict__ A,
                                                const unsigned short* __restrict__ Wq,
                                                const unsigned short* __restrict__ Wk,
                                                const unsigned short* __restrict__ Wv,
                                                unsigned short* __restrict__ Qo,
                                                unsigned short* __restrict__ Ko,
                                                unsigned short* __restrict__ Vo) {
  __shared__ __align__(16) unsigned short Ab[128 * 64];
  __shared__ __align__(16) unsigned short Bb[128 * 64];
  const int K = E_;
  const int tid = threadIdx.x;
  const int wid = tid >> 6;
  const int lr = tid & 15;
  const int lk = (tid >> 4) & 3;
  const int wr = wid >> 1, wc = wid & 1;
  const int m0 = blockIdx.x * 128;
  const int sel = blockIdx.y >> 3;
  const int n0 = (blockIdx.y & 7) * 128;
  const unsigned short* Bm = (sel == 0) ? Wq : (sel == 1) ? Wk : Wv;
  unsigned short* outp = (sel == 0) ? Qo : (sel == 1) ? Ko : Vo;

  f32x4 acc[4][4] = {};

  for (int k0 = 0; k0 < K; k0 += 64) {
    __syncthreads();
#pragma unroll
    for (int pass = 0; pass < 4; ++pass) {
      int chunk = pass * 256 + tid;
      int row = chunk >> 3, inner = chunk & 7;
      const unsigned short* ga = A + (size_t)(m0 + row) * K + k0 + inner * 8;
      const unsigned short* gb = Bm + (size_t)(n0 + row) * K + k0 + inner * 8;
      unsigned short* la = Ab + (size_t)(pass * 256 + wid * 64) * 8;
      unsigned short* lb = Bb + (size_t)(pass * 256 + wid * 64) * 8;
      GLOAD_LDS16(ga, la);
      GLOAD_LDS16(gb, lb);
    }
    __syncthreads();
#pragma unroll
    for (int kk = 0; kk < 2; ++kk) {
      short8 af[4], bf[4];
#pragma unroll
      for (int mi = 0; mi < 4; ++mi)
        af[mi] = *(const short8*)&Ab[(wr * 64 + mi * 16 + lr) * 64 + kk * 32 + lk * 8];
#pragma unroll
      for (int ni = 0; ni < 4; ++ni)
        bf[ni] = *(const short8*)&Bb[(wc * 64 + ni * 16 + lr) * 64 + kk * 32 + lk * 8];
#pragma unroll
      for (int mi = 0; mi < 4; ++mi)
#pragma unroll
        for (int ni = 0; ni < 4; ++ni)
          acc[mi][ni] = MFMA_BF16(af[mi], bf[ni], acc[mi][ni]);
    }
  }

#pragma unroll
  for (int mi = 0; mi < 4; ++mi)
#pragma unroll
    for (int ni = 0; ni < 4; ++ni) {
      int row0 = m0 + wr * 64 + mi * 16 + lk * 4;
      int col = n0 + wc * 64 + ni * 16 + lr;
      int b = row0 >> 11, t0 = row0 & (T_ - 1), h = col >> 6, d = col & (D_ - 1);
      if (sel == 2) {
        short4v vv;
#pragma unroll
        for (int r = 0; r < 4; ++r) vv[r] = (short)f2bf(acc[mi][ni][r]);
        *(short4v*)&outp[(((size_t)(b * H_ + h)) * D_ + d) * T_ + t0] = vv;  // [BH][D][T]
      } else {
#pragma unroll
        for (int r = 0; r < 4; ++r)
          outp[(((size_t)(b * H_ + h)) * T_ + t0 + r) * D_ + d] = f2bf(acc[mi][ni][r]);
      }
    }
}

// ---------------- out-proj GEMM: fp32 out + bias ----------------
__global__ __launch_bounds__(256) void gemm_out(const unsigned short* __restrict__ A,
                                                const unsigned short* __restrict__ Bm,
                                                float* __restrict__ outp,
                                                const float* __restrict__ bias,
                                                int M, int N, int K) {
  __shared__ __align__(16) unsigned short Ab[128 * 64];
  __shared__ __align__(16) unsigned short Bb[128 * 64];
  const int tid = threadIdx.x;
  const int wid = tid >> 6;
  const int lr = tid & 15;
  const int lk = (tid >> 4) & 3;
  const int wr = wid >> 1, wc = wid & 1;
  const int m0 = blockIdx.x * 128, n0 = blockIdx.y * 128;

  f32x4 acc[4][4] = {};

  for (int k0 = 0; k0 < K; k0 += 64) {
    __syncthreads();
#pragma unroll
    for (int pass = 0; pass < 4; ++pass) {
      int chunk = pass * 256 + tid;
      int row = chunk >> 3, inner = chunk & 7;
      const unsigned short* ga = A + (size_t)(m0 + row) * K + k0 + inner * 8;
      const unsigned short* gb = Bm + (size_t)(n0 + row) * K + k0 + inner * 8;
      unsigned short* la = Ab + (size_t)(pass * 256 + wid * 64) * 8;
      unsigned short* lb = Bb + (size_t)(pass * 256 + wid * 64) * 8;
      GLOAD_LDS16(ga, la);
      GLOAD_LDS16(gb, lb);
    }
    __syncthreads();
#pragma unroll
    for (int kk = 0; kk < 2; ++kk) {
      short8 af[4], bf[4];
#pragma unroll
      for (int mi = 0; mi < 4; ++mi)
        af[mi] = *(const short8*)&Ab[(wr * 64 + mi * 16 + lr) * 64 + kk * 32 + lk * 8];
#pragma unroll
      for (int ni = 0; ni < 4; ++ni)
        bf[ni] = *(const short8*)&Bb[(wc * 64 + ni * 16 + lr) * 64 + kk * 32 + lk * 8];
#pragma unroll
      for (int mi = 0; mi < 4; ++mi)
#pragma unroll
        for (int ni = 0; ni < 4; ++ni)
          acc[mi][ni] = MFMA_BF16(af[mi], bf[ni], acc[mi][ni]);
    }
  }

#pragma unroll
  for (int mi = 0; mi < 4; ++mi)
#pragma unroll
    for (int ni = 0; ni < 4; ++ni)
#pragma unroll
      for (int r = 0; r < 4; ++r) {
        int row = m0 + wr * 64 + mi * 16 + lk * 4 + r;
        int col = n0 + wc * 64 + ni * 16 + lr;
        outp[(size_t)row * N + col] = acc[mi][ni][r] + bias[col];
      }
}

// ---------------- fused causal flash attention ----------------
// 2048 blocks x 64 thr = 8 blocks/CU (all resident). Block = chunk pair
// (63-p, p), 32 rows each: exactly 33 tiles per block (perfect balance).
// Per chunk: r11's lagged-PV pipeline at HALF the accumulator state so
// 2 waves/SIMD fit the register file (r13 showed the 64-row body caps at 1):
//   iter i: {load K(i+1)->alt buf, V(i); QK(i); rowmax; PV(i-1) from other
//   P-buffer; rescale; pack(i)}. Named double buffers (no runtime index).
__device__ __forceinline__ void attn_group32(int chunk,
                                             const unsigned short* __restrict__ Qh,
                                             const unsigned short* __restrict__ Kh,
                                             const unsigned short* __restrict__ Vh,
                                             unsigned short* __restrict__ ctx,
                                             int b, int h2, int lane, int lr, int lk,
                                             char* bufA, char* bufB) {
  const float SC = 0.125f * 1.44269504089f;  // 1/sqrt(D) * log2(e)
  const int q0 = chunk * 32;
  const int nt = (q0 >> 6) + 1;
  const int ql0 = q0 & 63;  // 0 or 32

  short8 vones;
#pragma unroll
  for (int j = 0; j < 8; ++j) vones[j] = (short)0x3F80;  // bf16 1.0

  short8 qf[2][2];
#pragma unroll
  for (int a = 0; a < 2; ++a)
#pragma unroll
    for (int kb = 0; kb < 2; ++kb)
      qf[a][kb] = *(const short8*)&Qh[(size_t)(q0 + a * 16 + lr) * D_ + kb * 32 + lk * 8];

  f32x4 o[2][4] = {};
  f32x4 lsum[2] = {};
  float mrun[2] = {-1e30f, -1e30f};

  auto loadK = [&](short8(&kf)[2][4], int t) {
    const unsigned short* Kt = Kh + (size_t)t * 64 * D_;
#pragma unroll
    for (int kb = 0; kb < 2; ++kb)
#pragma unroll
      for (int n = 0; n < 4; ++n)
        kf[kb][n] = *(const short8*)&Kt[(size_t)(n * 16 + lr) * D_ + kb * 32 + lk * 8];
  };
  auto loadV = [&](short8(&v)[2][4], int t) {
    const unsigned short* Vtt = Vh + (size_t)t * 64;
#pragma unroll
    for (int kb = 0; kb < 2; ++kb)
#pragma unroll
      for (int nd = 0; nd < 4; ++nd)
        v[kb][nd] = *(const short8*)&Vtt[(size_t)(nd * 16 + lr) * T_ + kb * 32 + lk * 8];
  };
  auto pv = [&](char* buf, short8(&v)[2][4]) {
#pragma unroll
    for (int kb = 0; kb < 2; ++kb) {
      short8 pf0 = *(const short8*)(buf + (0 + lr) * 144 + kb * 64 + lk * 16);
      short8 pf1 = *(const short8*)(buf + (16 + lr) * 144 + kb * 64 + lk * 16);
#pragma unroll
      for (int nd = 0; nd < 4; ++nd) {
        o[0][nd] = MFMA_BF16(pf0, v[kb][nd], o[0][nd]);
        o[1][nd] = MFMA_BF16(pf1, v[kb][nd], o[1][nd]);
      }
      lsum[0] = MFMA_BF16(pf0, vones, lsum[0]);
      lsum[1] = MFMA_BF16(pf1, vones, lsum[1]);
    }
  };

  // per-tile body: QK(i) + rowmax + [PV(i-1)] + rescale + pack(i)
  auto tile = [&](int i, bool diag, bool doPV,
                  short8(&kfc)[2][4], short8(&kfn)[2][4],
                  short8(&vp)[2][4], short8(&vc)[2][4],
                  char* bufp, char* bufc, int tnext) {
    loadK(kfn, tnext);
    loadV(vc, i);
    f32x4 st[2][4] = {};
#pragma unroll
    for (int kb = 0; kb < 2; ++kb)
#pragma unroll
      for (int a = 0; a < 2; ++a)
#pragma unroll
        for (int n = 0; n < 4; ++n)
          st[a][n] = MFMA_BF16(kfc[kb][n], qf[a][kb], st[a][n]);
    if (diag) {
#pragma unroll
      for (int a = 0; a < 2; ++a)
#pragma unroll
        for (int n = 0; n < 4; ++n)
#pragma unroll
          for (int r = 0; r < 4; ++r)
            if (n * 16 + lk * 4 + r > ql0 + a * 16 + lr) st[a][n][r] = -3e38f;
    }
    float pm[2];
#pragma unroll
    for (int a = 0; a < 2; ++a) {
      float m0 = fmaxf(fmaxf(st[a][0][0], st[a][1][0]), fmaxf(st[a][2][0], st[a][3][0]));
      float m1 = fmaxf(fmaxf(st[a][0][1], st[a][1][1]), fmaxf(st[a][2][1], st[a][3][1]));
      float m2 = fmaxf(fmaxf(st[a][0][2], st[a][1][2]), fmaxf(st[a][2][2], st[a][3][2]));
      float m3 = fmaxf(fmaxf(st[a][0][3], st[a][1][3]), fmaxf(st[a][2][3], st[a][3][3]));
      float mx = fmaxf(fmaxf(m0, m1), fmaxf(m2, m3));
      mx = fmaxf(mx, __shfl_xor(mx, 16));
      mx = fmaxf(mx, __shfl_xor(mx, 32));
      pm[a] = mx * SC;
    }
    float need = fmaxf(pm[0] - mrun[0], pm[1] - mrun[1]);
    if (doPV) pv(bufp, vp);  // absorbs tile i-1 at OLD scale (before rescale)
    if (__any(need > 8.f)) {
#pragma unroll
      for (int a = 0; a < 2; ++a) {
        float mnew = fmaxf(mrun[a], pm[a]);
        float sc = exp2f(mrun[a] - mnew);
        mrun[a] = mnew;
#pragma unroll
        for (int r = 0; r < 4; ++r) {
          float sco = __shfl(sc, (lane & 48) | (lk * 4 + r));
          lsum[a][r] *= sco;
#pragma unroll
          for (int nd = 0; nd < 4; ++nd) o[a][nd][r] *= sco;
        }
      }
    }
#pragma unroll
    for (int a = 0; a < 2; ++a)
#pragma unroll
      for (int n = 0; n < 4; ++n) {
        float2 p01, p23;
        p01.x = exp2f(fmaf(st[a][n][0], SC, -mrun[a]));
        p01.y = exp2f(fmaf(st[a][n][1], SC, -mrun[a]));
        p23.x = exp2f(fmaf(st[a][n][2], SC, -mrun[a]));
        p23.y = exp2f(fmaf(st[a][n][3], SC, -mrun[a]));
        __hip_bfloat162 b01 = __float22bfloat162_rn(p01);
        __hip_bfloat162 b23 = __float22bfloat162_rn(p23);
        uint2 w;
        w.x = *(unsigned*)&b01;
        w.y = *(unsigned*)&b23;
        *(uint2*)(bufc + (a * 16 + lr) * 144 + n * 32 + lk * 8) = w;
      }
  };

  short8 kf0[2][4], kf1[2][4], v0[2][4], v1[2][4];

  // prologue: tile 0 (no PV), K(1) prefetched
  loadK(kf0, 0);
  tile(0, nt == 1, false, kf0, kf1, v1, v0, bufB, bufA, (1 < nt) ? 1 : 0);

  int i = 1;
  while (i < nt) {
    tile(i, i == nt - 1, true, kf1, kf0, v0, v1, bufA, bufB, (i + 1 < nt) ? i + 1 : i);
    if (++i >= nt) break;
    tile(i, i == nt - 1, true, kf0, kf1, v1, v0, bufB, bufA, (i + 1 < nt) ? i + 1 : i);
    ++i;
  }
  // epilogue: PV of last tile
  if ((nt - 1) & 1) pv(bufB, v1);
  else              pv(bufA, v0);

#pragma unroll
  for (int a = 0; a < 2; ++a)
#pragma unroll
    for (int r = 0; r < 4; ++r) {
      float inv = 1.0f / lsum[a][r];
      int t = q0 + a * 16 + lk * 4 + r;
#pragma unroll
      for (int nd = 0; nd < 4; ++nd)
        ctx[((size_t)b * T_ + t) * E_ + h2 * D_ + nd * 16 + lr] = f2bf(o[a][nd][r] * inv);
    }
}

__global__ __launch_bounds__(64) void attn_fused(const unsigned short* __restrict__ Q,
                                                 const unsigned short* __restrict__ K,
                                                 const unsigned short* __restrict__ VT,
                                                 unsigned short* __restrict__ ctx) {
  __shared__ __align__(16) unsigned short Pl[2][32 * 72];  // 2 bufs x 32 rows x 144B
  const int lane = threadIdx.x & 63;
  const int lr = lane & 15;
  const int lk = lane >> 4;

  // 2048 blocks = 8 XCD x 8 heads x 32 pairs; pair (63-p, p) => 33 tiles each.
  const int bid = blockIdx.x;
  const int xcd = bid & 7;
  const int p = bid >> 3;        // 0..255 per XCD
  const int bh = xcd * 8 + (p & 7);
  const int pr = p >> 3;         // 0..31

  const unsigned short* Qh = Q + (size_t)bh * T_ * D_;
  const unsigned short* Kh = K + (size_t)bh * T_ * D_;
  const unsigned short* Vh = VT + (size_t)bh * T_ * D_;  // [D][T]
  const int b = bh >> 4, h2 = bh & 15;
  char* bufA = (char*)&Pl[0][0];
  char* bufB = (char*)&Pl[1][0];

  attn_group32(63 - pr, Qh, Kh, Vh, ctx, b, h2, lane, lr, lk, bufA, bufB);
  attn_group32(pr,      Qh, Kh, Vh, ctx, b, h2, lane, lr, lk, bufA, bufB);
}

// ---------------- launcher ----------------
extern "C" void kernel_launch(void* const* d_in, const int* in_sizes, int n_in,
                              void* d_out, int out_size, void* d_ws, size_t ws_size,
                              hipStream_t stream) {
  const float* x    = (const float*)d_in[0];
  const float* Wq   = (const float*)d_in[1];
  const float* Wk   = (const float*)d_in[2];
  const float* Wv   = (const float*)d_in[3];
  const float* Wout = (const float*)d_in[4];
  const float* bout = (const float*)d_in[5];
  float* out = (float*)d_out;

  const size_t MT = (size_t)B_ * T_;      // 8192
  const size_t XE = MT * E_;              // 8,388,608
  const size_t WE = (size_t)E_ * E_;      // 1,048,576

  size_t need = (XE * 5 + WE * 4) * sizeof(unsigned short);
  if (ws_size < need) return;

  unsigned short* xb  = (unsigned short*)d_ws;
  unsigned short* wqb = xb + XE;
  unsigned short* wkb = wqb + WE;
  unsigned short* wvb = wkb + WE;
  unsigned short* wob = wvb + WE;
  unsigned short* Qb  = wob + WE;
  unsigned short* Kb  = Qb + XE;
  unsigned short* VTb = Kb + XE;
  unsigned short* ctx = VTb + XE;

  cvt_f32_bf16<<<(int)(XE / 8 / 256), 256, 0, stream>>>(x, xb, (int)(XE / 8));
  cvt_w4<<<2048, 256, 0, stream>>>(Wq, Wk, Wv, Wout, wqb);

  gemm_qkv<<<dim3(MT / 128, 24), 256, 0, stream>>>(xb, wqb, wkb, wvb, Qb, Kb, VTb);  // V written transposed

  attn_fused<<<2048, 64, 0, stream>>>(Qb, Kb, VTb, ctx);

  gemm_out<<<dim3(MT / 128, E_ / 128), 256, 0, stream>>>(ctx, wob, out, bout, (int)MT, E_, E_);
}